// Round 19
// baseline (539.324 us; speedup 1.0000x reference)
//
#include <hip/hip_runtime.h>
#include <hip/hip_bf16.h>
#include <math.h>

#define M_ 4096            // B*S
#define N_ 6144            // H*E
#define K_ 768             // H
#define H_ 768
#define L_ 2
#define NT 12              // K-tiles of BK=64

using bf16x8 = __attribute__((ext_vector_type(8))) short;
using f32x16 = __attribute__((ext_vector_type(16))) float;

__device__ __forceinline__ unsigned short f2bf(float f) {
  unsigned int u = __builtin_bit_cast(unsigned int, f);
  u += 0x7FFFu + ((u >> 16) & 1u);
  return (unsigned short)(u >> 16);
}

__device__ __forceinline__ float bf2f(unsigned short u) {
  return __builtin_bit_cast(float, (unsigned int)u << 16);
}

// tanh-form GELU: x*sigmoid(1.59576912x + 0.07135482x^3); max |err| vs exact ~3e-4
__device__ __forceinline__ float gelu_fast(float x) {
  float u2 = x * (1.5957691f + 0.07135481f * x * x);
  return x / (1.f + __expf(-u2));
}

// async global->LDS, 16B per lane. LDS dest must be wave-uniform base; HW adds lane*16.
__device__ __forceinline__ void gload_lds16(const void* g, void* l) {
  __builtin_amdgcn_global_load_lds(
      (__attribute__((address_space(1))) unsigned int*)(uintptr_t)g,
      (__attribute__((address_space(3))) unsigned int*)(unsigned int)(uintptr_t)l,
      16, 0, 0);
}

// W_exp layer-slab [3][768(k)][6144(n)] fp32 -> Wb [3][6144(n)][768(k)] bf16
__global__ __launch_bounds__(256) void conv_w(const float* __restrict__ W,
                                              short* __restrict__ Wb) {
  __shared__ float tile[64][65];
  const int z = blockIdx.z;            // tower
  const int n0 = blockIdx.x * 64;
  const int k0 = blockIdx.y * 64;
  const size_t inb  = (size_t)z * K_ * N_;
  const size_t outb = (size_t)z * N_ * K_;
  const int tid = threadIdx.x;
  const int c = tid & 63;
  const int r = tid >> 6;              // 0..3
#pragma unroll
  for (int p = 0; p < 16; ++p) {
    const int kk = p * 4 + r;
    tile[c][kk] = W[inb + (size_t)(k0 + kk) * N_ + n0 + c];
  }
  __syncthreads();
#pragma unroll
  for (int p = 0; p < 16; ++p) {
    const int nn = p * 4 + r;
    Wb[outb + (size_t)(n0 + nn) * K_ + k0 + c] = (short)f2bf(tile[nn][c]);
  }
}

// gate logits + softmax from LDS-cached bf16 weights; p[] in registers (template NG)
template<int NG>
__device__ __forceinline__ void gate_sm(const float x[12],
    const unsigned short* Wlds, const float* __restrict__ bg,
    float* __restrict__ grow, int lane) {
  float p[NG];
#pragma unroll
  for (int j = 0; j < NG; ++j) {
    const unsigned short* wr = Wlds + j * 768 + lane * 4;
    ushort4 wa = *(const ushort4*)wr;
    ushort4 wb = *(const ushort4*)(wr + 256);
    ushort4 wc = *(const ushort4*)(wr + 512);
    p[j] = bf2f(wa.x) * x[0] + bf2f(wa.y) * x[1] + bf2f(wa.z) * x[2]  + bf2f(wa.w) * x[3]
         + bf2f(wb.x) * x[4] + bf2f(wb.y) * x[5] + bf2f(wb.z) * x[6]  + bf2f(wb.w) * x[7]
         + bf2f(wc.x) * x[8] + bf2f(wc.y) * x[9] + bf2f(wc.z) * x[10] + bf2f(wc.w) * x[11];
  }
#pragma unroll
  for (int j = 0; j < NG; ++j)
#pragma unroll
    for (int m = 1; m < 64; m <<= 1) p[j] += __shfl_xor(p[j], m);
  float mx = -1e30f;
#pragma unroll
  for (int j = 0; j < NG; ++j) { p[j] += bg[j]; mx = fmaxf(mx, p[j]); }
  float s = 0.f;
#pragma unroll
  for (int j = 0; j < NG; ++j) { p[j] = __expf(p[j] - mx); s += p[j]; }
  const float inv = 1.f / s;
  if (lane == 0) {
#pragma unroll
    for (int j = 0; j < NG; ++j) grow[j] = p[j] * inv;
  }
}

// ------------------------------- LN + gates, block = 16 rows of ONE tower.
// part streams: s0:t0->sh s1:t0->t1 s2:t0->t2 s3:t1->sh s4:t1->t1 s5:t2->sh s6:t2->t2
// mode 0: x = raw input.  mode 1: x = raw input + layer-0 partials; write h = x.
__global__ __launch_bounds__(256, 4) void ln_gates(
    const float* __restrict__ in0, const float* __restrict__ in1,
    const float* __restrict__ in2,
    float* __restrict__ h,                  // [3][M][H] (written when mode==1)
    const unsigned short* __restrict__ part,// [7][M][H] bf16
    int mode,
    short* __restrict__ xs,                 // [3][M][K] bf16
    const float* __restrict__ ln_g,         // [3][H] this layer
    const float* __restrict__ ln_b,
    const float* __restrict__ Wg_sh, const float* __restrict__ bg_sh,   // per-layer
    const float* __restrict__ Wg_t1, const float* __restrict__ bg_t1,
    const float* __restrict__ Wg_t2, const float* __restrict__ bg_t2,
    float* __restrict__ gates)              // g_sh [M][24]; g_t1 [M][16]; g_t2 [M][16]
{
  __shared__ unsigned short Wlds[24 * 768];   // 36,864 B; bf16 [NG][768]

  const int b = blockIdx.x;            // 768 = 3 towers x 256 blocks x 16 rows
  const int t = b >> 8;
  const int rbase = (b & 255) * 16;
  const int w = threadIdx.x >> 6, lane = threadIdx.x & 63;

  // ---- one-time: load tower's gate weights [768][NG] -> LDS bf16 [NG][768] ----
  if (t == 0) {
    for (int i4 = threadIdx.x; i4 < 768 * 24 / 4; i4 += 256) {
      float4 v = ((const float4*)Wg_sh)[i4];
      const int e0 = i4 * 4;
#pragma unroll
      for (int k2 = 0; k2 < 4; ++k2) {
        const int e = e0 + k2, i = e / 24, j = e - i * 24;
        Wlds[j * 768 + i] = f2bf(((const float*)&v)[k2]);
      }
    }
  } else {
    const float* Wg = (t == 1) ? Wg_t1 : Wg_t2;
    for (int i4 = threadIdx.x; i4 < 768 * 16 / 4; i4 += 256) {
      float4 v = ((const float4*)Wg)[i4];
      const int e0 = i4 * 4;
#pragma unroll
      for (int k2 = 0; k2 < 4; ++k2) {
        const int e = e0 + k2;
        Wlds[(e & 15) * 768 + (e >> 4)] = f2bf(((const float*)&v)[k2]);
      }
    }
  }
  __syncthreads();

  const size_t MH = (size_t)M_ * H_;
  const float* inp = (t == 0) ? in0 : (t == 1) ? in1 : in2;

  for (int r = 0; r < 4; ++r) {
    const int row = rbase + w * 4 + r;
    const float* srow = inp + (size_t)row * H_;
    float* hrow = h + ((size_t)t * M_ + row) * H_;

    const unsigned short *pa = nullptr, *pb = nullptr, *pc = nullptr;
    if (mode) {
      if (t == 0)      { pa = part + (size_t)row * H_;          pb = part + 3 * MH + (size_t)row * H_; pc = part + 5 * MH + (size_t)row * H_; }
      else if (t == 1) { pa = part + 1 * MH + (size_t)row * H_; pb = part + 4 * MH + (size_t)row * H_; }
      else             { pa = part + 2 * MH + (size_t)row * H_; pb = part + 6 * MH + (size_t)row * H_; }
    }

    float x[12];
    float sum = 0.f, ss = 0.f;
#pragma unroll
    for (int q = 0; q < 3; ++q) {
      const int o = q * 256 + lane * 4;
      float4 v = *(const float4*)(srow + o);
      if (mode) {
        ushort4 a4 = *(const ushort4*)(pa + o);
        ushort4 b4 = *(const ushort4*)(pb + o);
        v.x += bf2f(a4.x) + bf2f(b4.x);
        v.y += bf2f(a4.y) + bf2f(b4.y);
        v.z += bf2f(a4.z) + bf2f(b4.z);
        v.w += bf2f(a4.w) + bf2f(b4.w);
        if (t == 0) {
          ushort4 c4 = *(const ushort4*)(pc + o);
          v.x += bf2f(c4.x); v.y += bf2f(c4.y); v.z += bf2f(c4.z); v.w += bf2f(c4.w);
        }
        *(float4*)(hrow + o) = v;   // residual state write-back
      }
      x[q * 4 + 0] = v.x; x[q * 4 + 1] = v.y; x[q * 4 + 2] = v.z; x[q * 4 + 3] = v.w;
      sum += v.x + v.y + v.z + v.w;
      ss  += v.x * v.x + v.y * v.y + v.z * v.z + v.w * v.w;
    }
#pragma unroll
    for (int m = 1; m < 64; m <<= 1) { sum += __shfl_xor(sum, m); ss += __shfl_xor(ss, m); }
    const float mean = sum * (1.f / 768.f);
    float var = ss * (1.f / 768.f) - mean * mean;
    var = var < 0.f ? 0.f : var;
    const float rstd = rsqrtf(var + 1e-5f);

    const float* ga = ln_g + (size_t)t * H_;
    const float* be = ln_b + (size_t)t * H_;
    short* xrow = xs + ((size_t)t * M_ + row) * K_;
#pragma unroll
    for (int q = 0; q < 3; ++q) {
      float4 g4 = *(const float4*)(ga + q * 256 + lane * 4);
      float4 b4 = *(const float4*)(be + q * 256 + lane * 4);
      float y0 = g4.x * (x[q * 4 + 0] - mean) * rstd + b4.x;
      float y1 = g4.y * (x[q * 4 + 1] - mean) * rstd + b4.y;
      float y2 = g4.z * (x[q * 4 + 2] - mean) * rstd + b4.z;
      float y3 = g4.w * (x[q * 4 + 3] - mean) * rstd + b4.w;
      x[q * 4 + 0] = y0; x[q * 4 + 1] = y1; x[q * 4 + 2] = y2; x[q * 4 + 3] = y3;
      ushort4 st; st.x = f2bf(y0); st.y = f2bf(y1); st.z = f2bf(y2); st.w = f2bf(y3);
      *(ushort4*)(xrow + q * 256 + lane * 4) = st;
    }

    // ---- gates from LDS weights ----
    if (t == 0) {
      gate_sm<24>(x, Wlds, bg_sh, gates + (size_t)row * 24, lane);
    } else if (t == 1) {
      gate_sm<16>(x, Wlds, bg_t1, gates + (size_t)M_ * 24 + (size_t)row * 16, lane);
    } else {
      gate_sm<16>(x, Wlds, bg_t2, gates + (size_t)M_ * 24 + (size_t)M_ * 16 + (size_t)row * 16, lane);
    }
  }
}

// -------------- expert GEMM: 128x128 tile, BK=64, NT=12, 32x32x16 MFMA
// (R18 staging/swizzle/supertile frozen; inner loop swapped 32x 16x16x32 -> 16x 32x32x16:
//  ~17% less matrix-pipe time at the higher 32x32 ceiling, half the issue slots.
//  C/D map [m74/m101]: row=(reg&3)+8*(reg>>2)+4*(lane>>5), col=lane&31.)
__global__ __launch_bounds__(256, 2) void expert_gemm(
    const short* __restrict__ xs,      // [3][M][K]
    const short* __restrict__ Wb,      // [3][N][K] this layer
    const float* __restrict__ b_exp_l, // [3][N] this layer
    const float* __restrict__ g_sh,
    const float* __restrict__ g_t1,
    const float* __restrict__ g_t2,
    unsigned short* __restrict__ part) // [7][M][H] bf16
{
  __shared__ short lds[16640];  // 33,280 B: staging 32 KiB | epilogue wtile 4x(32x65 f32)

  const int bid = blockIdx.x;          // 4608 = 8 XCDs x 576
  const int xcd = bid & 7;
  const int idx = bid >> 3;            // 0..575
  const int t   = idx / 192;
  const int r2  = idx - t * 192;
  const int mt  = r2 / 6;
  const int m0  = mt * 128;
  const int n0  = (xcd * 6 + (r2 - mt * 6)) * 128;

  const short* A  = xs + (size_t)t * M_ * K_;
  const short* Bt = Wb + (size_t)t * N_ * K_;

  const int tid = threadIdx.x;
  const int w = tid >> 6, l = tid & 63;
  const int wr = w >> 1, wc = w & 1;   // 2 x 2 wave grid; per-wave 64x64

  // 32x32x16 operand frags: row r32 = l&31, k-half kh = l>>5 (8 k each).
  // For ks (0..3): colgroup cg = ks*2 + kh; stored phys slot = cg ^ ((row>>1)&7).
  const int r32 = l & 31, kh = l >> 5;
  const int fx32 = (r32 >> 1) & 7;
  int slotk[4];
#pragma unroll
  for (int ks = 0; ks < 4; ++ks) slotk[ks] = (((ks * 2 + kh) ^ fx32) << 3);  // shorts

  f32x16 acc[2][2];
#pragma unroll
  for (int i = 0; i < 2; ++i)
#pragma unroll
    for (int j = 0; j < 2; ++j)
#pragma unroll
      for (int e = 0; e < 16; ++e) acc[i][j][e] = 0.f;

  // staging: 4 rounds x (1 A + 1 B) gload_lds16; dest row = w*32+q*8+(l>>3), slot = l&7.
  // T2 swizzle inverse on global source: logical colgroup = (l&7) ^ ((q*4 + (l>>4)) & 7).
  for (int kt = 0; kt < NT; ++kt) {
    __syncthreads();                             // prev tile fully consumed
#pragma unroll
    for (int q = 0; q < 4; ++q) {
      const int row = w * 32 + q * 8 + (l >> 3);
      const int fq = (q * 4 + (l >> 4)) & 7;
      const int csw = ((l & 7) ^ fq) << 3;       // shorts
      gload_lds16(A  + (size_t)(m0 + row) * K_ + kt * 64 + csw, &lds[(w * 32 + q * 8) * 64]);
      gload_lds16(Bt + (size_t)(n0 + row) * K_ + kt * 64 + csw, &lds[8192 + (w * 32 + q * 8) * 64]);
    }
    __syncthreads();                             // staged tile visible (barrier drains vmcnt)

    bf16x8 a[2][4], b[2][4];
#pragma unroll
    for (int fm = 0; fm < 2; ++fm)
#pragma unroll
      for (int ks = 0; ks < 4; ++ks)
        a[fm][ks] = *(const bf16x8*)&lds[wr * 4096 + (fm * 32 + r32) * 64 + slotk[ks]];
#pragma unroll
    for (int fn = 0; fn < 2; ++fn)
#pragma unroll
      for (int ks = 0; ks < 4; ++ks)
        b[fn][ks] = *(const bf16x8*)&lds[8192 + wc * 4096 + (fn * 32 + r32) * 64 + slotk[ks]];
    __builtin_amdgcn_s_setprio(1);
#pragma unroll
    for (int ks = 0; ks < 4; ++ks)
#pragma unroll
      for (int fm = 0; fm < 2; ++fm)
#pragma unroll
        for (int fn = 0; fn < 2; ++fn)
          acc[fm][fn] = __builtin_amdgcn_mfma_f32_32x32x16_bf16(a[fm][ks], b[fn][ks], acc[fm][fn], 0, 0, 0);
    __builtin_amdgcn_s_setprio(0);
  }
  __syncthreads();   // staging LDS dead; safe to reuse for transpose

  // ---- epilogue: bias + gelu via wave-private LDS transpose + gated combine ----
  const size_t MH = (size_t)M_ * H_;
  const float *gpA, *gpB, *gpC = nullptr;
  unsigned short *ppA, *ppB, *ppC = nullptr;
  int ldA, ldB, ldC = 16, offA, offB, offC = 0, ntg;
  if (t == 0) {
    gpA = g_sh; ldA = 24; offA = 8; ppA = part;
    gpB = g_t1; ldB = 16; offB = 8; ppB = part + 1 * MH;
    gpC = g_t2; ldC = 16; offC = 8; ppC = part + 2 * MH; ntg = 3;
  } else if (t == 1) {
    gpA = g_sh; ldA = 24; offA = 0; ppA = part + 3 * MH;
    gpB = g_t1; ldB = 16; offB = 0; ppB = part + 4 * MH; ntg = 2;
  } else {
    gpA = g_sh; ldA = 24; offA = 16; ppA = part + 5 * MH;
    gpB = g_t2; ldB = 16; offB = 0;  ppB = part + 6 * MH; ntg = 2;
  }
  // per-lane bias for cols n = n0 + wc*64 + fn*32 + (l&31)
  const float* be = b_exp_l + (size_t)t * N_ + n0 + wc * 64 + r32;
  float bias2[2];
  bias2[0] = be[0];
  bias2[1] = be[32];

  float* wtile = (float*)lds + w * 2080;         // 32 x 65 floats, wave-private
  const int xbase = (n0 + wc * 64) >> 3;
  const int xloc = l & 7;

#pragma unroll
  for (int fm = 0; fm < 2; ++fm) {
    // write 32 bias+gelu'd values into [32][65] tile
    asm volatile("s_waitcnt lgkmcnt(0)" ::: "memory");  // WAR vs prev fm's reads
#pragma unroll
    for (int fn = 0; fn < 2; ++fn)
#pragma unroll
      for (int reg = 0; reg < 16; ++reg) {
        const int mloc = (reg & 3) + 8 * (reg >> 2) + 4 * kh;
        wtile[mloc * 65 + fn * 32 + r32] = gelu_fast(acc[fm][fn][reg] + bias2[fn]);
      }
    asm volatile("s_waitcnt lgkmcnt(0)" ::: "memory");  // RAW: writes visible to wave

    // read back: 4 (m,x) pairs per lane, 8 consecutive e-values each
    float v[4][8];
    int gm[4];
#pragma unroll
    for (int p = 0; p < 4; ++p) {
      const int mloc = p * 8 + (l >> 3);
      float4 v0 = *(const float4*)&wtile[mloc * 65 + xloc * 8];
      float4 v1 = *(const float4*)&wtile[mloc * 65 + xloc * 8 + 4];
      v[p][0] = v0.x; v[p][1] = v0.y; v[p][2] = v0.z; v[p][3] = v0.w;
      v[p][4] = v1.x; v[p][5] = v1.y; v[p][6] = v1.z; v[p][7] = v1.w;
      gm[p] = m0 + wr * 64 + fm * 32 + mloc;
    }

    // per stream: 2 float4 gate loads + 8 FMA + 1 bf16 store per (m,x)
#define DO_STREAM(gp, ldg, offg, pp)                                          \
    {                                                                         \
      _Pragma("unroll")                                                       \
      for (int p = 0; p < 4; ++p) {                                           \
        const float* gr = (gp) + (size_t)gm[p] * (ldg) + (offg);              \
        float4 ga = *(const float4*)gr;                                       \
        float4 gb = *(const float4*)(gr + 4);                                 \
        float o = ga.x * v[p][0] + ga.y * v[p][1] + ga.z * v[p][2]            \
                + ga.w * v[p][3] + gb.x * v[p][4] + gb.y * v[p][5]            \
                + gb.z * v[p][6] + gb.w * v[p][7];                            \
        (pp)[(size_t)gm[p] * H_ + xbase + xloc] = f2bf(o);                    \
      }                                                                       \
    }
    DO_STREAM(gpA, ldA, offA, ppA);
    DO_STREAM(gpB, ldB, offB, ppB);
    if (ntg == 3) DO_STREAM(gpC, ldC, offC, ppC);
#undef DO_STREAM
  }
}

// --------------------------------------------------------------- output heads
// 4 rows per block (512 thr): head-weight L2 re-reads divided by 4 vs 1-row blocks.
__global__ __launch_bounds__(512) void heads(
    const float* __restrict__ h,
    const unsigned short* __restrict__ part,
    const float* __restrict__ Wspan, const float* __restrict__ bspan,
    const float* __restrict__ Was,   const float* __restrict__ bas,
    const float* __restrict__ Wae,   const float* __restrict__ bae,
    float* __restrict__ out)
{
  const int base = blockIdx.x * 4;
  __shared__ float s1[4][768], s2[4][768];
  const size_t MH = (size_t)M_ * H_;
  for (int idx = threadIdx.x; idx < 4 * 768; idx += 512) {
    const int rr = idx / 768, i = idx - rr * 768;
    const int row = base + rr;
    s1[rr][i] = h[((size_t)M_ + row) * H_ + i]
              + bf2f(part[1 * MH + (size_t)row * H_ + i])
              + bf2f(part[4 * MH + (size_t)row * H_ + i]);
    s2[rr][i] = h[((size_t)2 * M_ + row) * H_ + i]
              + bf2f(part[2 * MH + (size_t)row * H_ + i])
              + bf2f(part[6 * MH + (size_t)row * H_ + i]);
  }
  __syncthreads();
  const int r = threadIdx.x >> 7;      // 0..3
  const int j = threadIdx.x & 127;
  const int row = base + r;
  const float* W; const float* src; float bias; float* op; int ldw;
  if (j < 5)       { W = Wspan + j;      src = s1[r]; bias = bspan[j];  op = out + (size_t)row * 5 + j;                ldw = 5;  }
  else if (j < 36) { W = Was + (j - 5);  src = s2[r]; bias = bas[j-5];  op = out + 20480 + (size_t)row * 31 + (j-5);   ldw = 31; }
  else if (j < 67) { W = Wae + (j - 36); src = s2[r]; bias = bae[j-36]; op = out + 147456 + (size_t)row * 31 + (j-36); ldw = 31; }
  else return;
  float acc = bias;
  for (int i = 0; i < 768; ++i) acc += src[i] * W[(size_t)i * ldw];
  *op = acc;
}

// ---------------------------------------------------------------------- launch
extern "C" void kernel_launch(void* const* d_in, const int* in_sizes, int n_in,
                              void* d_out, int out_size, void* d_ws, size_t ws_size,
                              hipStream_t stream) {
  (void)in_sizes; (void)n_in; (void)out_size; (void)ws_size;
  const float* share  = (const float*)d_in[0];
  const float* span   = (const float*)d_in[1];
  const float* attr   = (const float*)d_in[2];
  const float* ln_g   = (const float*)d_in[3];
  const float* ln_b   = (const float*)d_in[4];
  const float* W_exp  = (const float*)d_in[5];
  const float* b_exp  = (const float*)d_in[6];
  const float* Wg_sh  = (const float*)d_in[7];
  const float* bg_sh  = (const float*)d_in[8];
  const float* Wg_t1  = (const float*)d_in[9];
  const float* bg_t1  = (const float*)d_in[10];
  const float* Wg_t2  = (const float*)d_in[11];
  const float* bg_t2  = (const float*)d_in[12];
  const float* W_span = (const float*)d_in[13];
  const float* b_span = (const float*)d_in[14];
  const float* W_as   = (const float*)d_in[15];
  const float* b_as   = (const float*)d_in[16];
  const float* W_ae   = (const float*)d_in[17];
  const float* b_ae   = (const float*)d_in[18];

  // workspace layout (~126 MiB)
  char* ws = (char*)d_ws;
  short* Wb = (short*)ws;                                        // [3][N][K] bf16 (per layer)
  size_t o = (size_t)3 * N_ * K_ * 2;                            // 28,311,552
  short* xs = (short*)(ws + o); o += (size_t)3 * M_ * K_ * 2;    // 18,874,368
  float* h  = (float*)(ws + o); o += (size_t)3 * M_ * H_ * 4;    // 37,748,736
  float* gates = (float*)(ws + o); o += (size_t)M_ * (24 + 16 + 16) * 4;  // 917,504
  unsigned short* part = (unsigned short*)(ws + o);              // [7][M][H] bf16: 44,040,192

  for (int l = 0; l < L_; ++l) {
    conv_w<<<dim3(96, 12, 3), 256, 0, stream>>>(
        W_exp + (size_t)l * 3 * K_ * N_, Wb);
    ln_gates<<<768, 256, 0, stream>>>(
        share, span, attr, h, part, l, xs,
        ln_g + (size_t)l * 3 * H_, ln_b + (size_t)l * 3 * H_,
        Wg_sh + (size_t)l * H_ * 24, bg_sh + (size_t)l * 24,
        Wg_t1 + (size_t)l * H_ * 16, bg_t1 + (size_t)l * 16,
        Wg_t2 + (size_t)l * H_ * 16, bg_t2 + (size_t)l * 16,
        gates);
    expert_gemm<<<4608, 256, 0, stream>>>(
        xs, Wb, b_exp + (size_t)l * 3 * N_,
        gates, gates + (size_t)M_ * 24, gates + (size_t)M_ * 24 + (size_t)M_ * 16,
        part);
  }

  heads<<<1024, 512, 0, stream>>>(h, part, W_span, b_span, W_as, b_as, W_ae, b_ae,
                                  (float*)d_out);
}

// Round 20
// 489.245 us; speedup vs baseline: 1.1024x; 1.1024x over previous
//
#include <hip/hip_runtime.h>
#include <hip/hip_bf16.h>
#include <math.h>

#define M_ 4096            // B*S
#define N_ 6144            // H*E
#define K_ 768             // H
#define H_ 768
#define L_ 2
#define NT 12              // K-tiles of BK=64 (768/64; bias handled in epilogue)

using bf16x8 = __attribute__((ext_vector_type(8))) short;
using f32x4  = __attribute__((ext_vector_type(4))) float;

__device__ __forceinline__ unsigned short f2bf(float f) {
  unsigned int u = __builtin_bit_cast(unsigned int, f);
  u += 0x7FFFu + ((u >> 16) & 1u);
  return (unsigned short)(u >> 16);
}

__device__ __forceinline__ float bf2f(unsigned short u) {
  return __builtin_bit_cast(float, (unsigned int)u << 16);
}

// tanh-form GELU: x*sigmoid(1.59576912x + 0.07135482x^3); max |err| vs exact ~3e-4
__device__ __forceinline__ float gelu_fast(float x) {
  float u2 = x * (1.5957691f + 0.07135481f * x * x);
  return x / (1.f + __expf(-u2));
}

// async global->LDS, 16B per lane. LDS dest must be wave-uniform base; HW adds lane*16.
__device__ __forceinline__ void gload_lds16(const void* g, void* l) {
  __builtin_amdgcn_global_load_lds(
      (__attribute__((address_space(1))) unsigned int*)(uintptr_t)g,
      (__attribute__((address_space(3))) unsigned int*)(unsigned int)(uintptr_t)l,
      16, 0, 0);
}

// W_exp layer-slab [3][768(k)][6144(n)] fp32 -> Wb [3][6144(n)][768(k)] bf16
__global__ __launch_bounds__(256) void conv_w(const float* __restrict__ W,
                                              short* __restrict__ Wb) {
  __shared__ float tile[64][65];
  const int z = blockIdx.z;            // tower
  const int n0 = blockIdx.x * 64;
  const int k0 = blockIdx.y * 64;
  const size_t inb  = (size_t)z * K_ * N_;
  const size_t outb = (size_t)z * N_ * K_;
  const int tid = threadIdx.x;
  const int c = tid & 63;
  const int r = tid >> 6;              // 0..3
#pragma unroll
  for (int p = 0; p < 16; ++p) {
    const int kk = p * 4 + r;
    tile[c][kk] = W[inb + (size_t)(k0 + kk) * N_ + n0 + c];
  }
  __syncthreads();
#pragma unroll
  for (int p = 0; p < 16; ++p) {
    const int nn = p * 4 + r;
    Wb[outb + (size_t)(n0 + nn) * K_ + k0 + c] = (short)f2bf(tile[nn][c]);
  }
}

// gate logits + softmax from LDS-cached bf16 weights; p[] in registers (template NG)
template<int NG>
__device__ __forceinline__ void gate_sm(const float x[12],
    const unsigned short* Wlds, const float* __restrict__ bg,
    float* __restrict__ grow, int lane) {
  float p[NG];
#pragma unroll
  for (int j = 0; j < NG; ++j) {
    const unsigned short* wr = Wlds + j * 768 + lane * 4;
    ushort4 wa = *(const ushort4*)wr;
    ushort4 wb = *(const ushort4*)(wr + 256);
    ushort4 wc = *(const ushort4*)(wr + 512);
    p[j] = bf2f(wa.x) * x[0] + bf2f(wa.y) * x[1] + bf2f(wa.z) * x[2]  + bf2f(wa.w) * x[3]
         + bf2f(wb.x) * x[4] + bf2f(wb.y) * x[5] + bf2f(wb.z) * x[6]  + bf2f(wb.w) * x[7]
         + bf2f(wc.x) * x[8] + bf2f(wc.y) * x[9] + bf2f(wc.z) * x[10] + bf2f(wc.w) * x[11];
  }
#pragma unroll
  for (int j = 0; j < NG; ++j)
#pragma unroll
    for (int m = 1; m < 64; m <<= 1) p[j] += __shfl_xor(p[j], m);
  float mx = -1e30f;
#pragma unroll
  for (int j = 0; j < NG; ++j) { p[j] += bg[j]; mx = fmaxf(mx, p[j]); }
  float s = 0.f;
#pragma unroll
  for (int j = 0; j < NG; ++j) { p[j] = __expf(p[j] - mx); s += p[j]; }
  const float inv = 1.f / s;
  if (lane == 0) {
#pragma unroll
    for (int j = 0; j < NG; ++j) grow[j] = p[j] * inv;
  }
}

// ------------------------------- LN + gates, block = 16 rows of ONE tower.
// Gate weights cached in LDS (bf16) once per block (~23 MB total weight traffic).
// part streams: s0:t0->sh s1:t0->t1 s2:t0->t2 s3:t1->sh s4:t1->t1 s5:t2->sh s6:t2->t2
// mode 0: x = raw input.  mode 1: x = raw input + layer-0 partials; write h = x.
__global__ __launch_bounds__(256, 4) void ln_gates(
    const float* __restrict__ in0, const float* __restrict__ in1,
    const float* __restrict__ in2,
    float* __restrict__ h,                  // [3][M][H] (written when mode==1)
    const unsigned short* __restrict__ part,// [7][M][H] bf16
    int mode,
    short* __restrict__ xs,                 // [3][M][K] bf16
    const float* __restrict__ ln_g,         // [3][H] this layer
    const float* __restrict__ ln_b,
    const float* __restrict__ Wg_sh, const float* __restrict__ bg_sh,   // per-layer
    const float* __restrict__ Wg_t1, const float* __restrict__ bg_t1,
    const float* __restrict__ Wg_t2, const float* __restrict__ bg_t2,
    float* __restrict__ gates)              // g_sh [M][24]; g_t1 [M][16]; g_t2 [M][16]
{
  __shared__ unsigned short Wlds[24 * 768];   // 36,864 B; bf16 [NG][768]

  const int b = blockIdx.x;            // 768 = 3 towers x 256 blocks x 16 rows
  const int t = b >> 8;
  const int rbase = (b & 255) * 16;
  const int w = threadIdx.x >> 6, lane = threadIdx.x & 63;

  // ---- one-time: load tower's gate weights [768][NG] -> LDS bf16 [NG][768] ----
  if (t == 0) {
    for (int i4 = threadIdx.x; i4 < 768 * 24 / 4; i4 += 256) {
      float4 v = ((const float4*)Wg_sh)[i4];
      const int e0 = i4 * 4;
#pragma unroll
      for (int k2 = 0; k2 < 4; ++k2) {
        const int e = e0 + k2, i = e / 24, j = e - i * 24;
        Wlds[j * 768 + i] = f2bf(((const float*)&v)[k2]);
      }
    }
  } else {
    const float* Wg = (t == 1) ? Wg_t1 : Wg_t2;
    for (int i4 = threadIdx.x; i4 < 768 * 16 / 4; i4 += 256) {
      float4 v = ((const float4*)Wg)[i4];
      const int e0 = i4 * 4;
#pragma unroll
      for (int k2 = 0; k2 < 4; ++k2) {
        const int e = e0 + k2;
        Wlds[(e & 15) * 768 + (e >> 4)] = f2bf(((const float*)&v)[k2]);
      }
    }
  }
  __syncthreads();

  const size_t MH = (size_t)M_ * H_;
  const float* inp = (t == 0) ? in0 : (t == 1) ? in1 : in2;

  for (int r = 0; r < 4; ++r) {
    const int row = rbase + w * 4 + r;
    const float* srow = inp + (size_t)row * H_;
    float* hrow = h + ((size_t)t * M_ + row) * H_;

    const unsigned short *pa = nullptr, *pb = nullptr, *pc = nullptr;
    if (mode) {
      if (t == 0)      { pa = part + (size_t)row * H_;          pb = part + 3 * MH + (size_t)row * H_; pc = part + 5 * MH + (size_t)row * H_; }
      else if (t == 1) { pa = part + 1 * MH + (size_t)row * H_; pb = part + 4 * MH + (size_t)row * H_; }
      else             { pa = part + 2 * MH + (size_t)row * H_; pb = part + 6 * MH + (size_t)row * H_; }
    }

    float x[12];
    float sum = 0.f, ss = 0.f;
#pragma unroll
    for (int q = 0; q < 3; ++q) {
      const int o = q * 256 + lane * 4;
      float4 v = *(const float4*)(srow + o);
      if (mode) {
        ushort4 a4 = *(const ushort4*)(pa + o);
        ushort4 b4 = *(const ushort4*)(pb + o);
        v.x += bf2f(a4.x) + bf2f(b4.x);
        v.y += bf2f(a4.y) + bf2f(b4.y);
        v.z += bf2f(a4.z) + bf2f(b4.z);
        v.w += bf2f(a4.w) + bf2f(b4.w);
        if (t == 0) {
          ushort4 c4 = *(const ushort4*)(pc + o);
          v.x += bf2f(c4.x); v.y += bf2f(c4.y); v.z += bf2f(c4.z); v.w += bf2f(c4.w);
        }
        *(float4*)(hrow + o) = v;   // residual state write-back
      }
      x[q * 4 + 0] = v.x; x[q * 4 + 1] = v.y; x[q * 4 + 2] = v.z; x[q * 4 + 3] = v.w;
      sum += v.x + v.y + v.z + v.w;
      ss  += v.x * v.x + v.y * v.y + v.z * v.z + v.w * v.w;
    }
#pragma unroll
    for (int m = 1; m < 64; m <<= 1) { sum += __shfl_xor(sum, m); ss += __shfl_xor(ss, m); }
    const float mean = sum * (1.f / 768.f);
    float var = ss * (1.f / 768.f) - mean * mean;
    var = var < 0.f ? 0.f : var;
    const float rstd = rsqrtf(var + 1e-5f);

    const float* ga = ln_g + (size_t)t * H_;
    const float* be = ln_b + (size_t)t * H_;
    short* xrow = xs + ((size_t)t * M_ + row) * K_;
#pragma unroll
    for (int q = 0; q < 3; ++q) {
      float4 g4 = *(const float4*)(ga + q * 256 + lane * 4);
      float4 b4 = *(const float4*)(be + q * 256 + lane * 4);
      float y0 = g4.x * (x[q * 4 + 0] - mean) * rstd + b4.x;
      float y1 = g4.y * (x[q * 4 + 1] - mean) * rstd + b4.y;
      float y2 = g4.z * (x[q * 4 + 2] - mean) * rstd + b4.z;
      float y3 = g4.w * (x[q * 4 + 3] - mean) * rstd + b4.w;
      x[q * 4 + 0] = y0; x[q * 4 + 1] = y1; x[q * 4 + 2] = y2; x[q * 4 + 3] = y3;
      ushort4 st; st.x = f2bf(y0); st.y = f2bf(y1); st.z = f2bf(y2); st.w = f2bf(y3);
      *(ushort4*)(xrow + q * 256 + lane * 4) = st;
    }

    // ---- gates from LDS weights ----
    if (t == 0) {
      gate_sm<24>(x, Wlds, bg_sh, gates + (size_t)row * 24, lane);
    } else if (t == 1) {
      gate_sm<16>(x, Wlds, bg_t1, gates + (size_t)M_ * 24 + (size_t)row * 16, lane);
    } else {
      gate_sm<16>(x, Wlds, bg_t2, gates + (size_t)M_ * 24 + (size_t)M_ * 16 + (size_t)row * 16, lane);
    }
  }
}

// -------------- expert GEMM: 128x128 tile, BK=64, NT=12, 32 KiB LDS (R9 champion
// structure; bias applied in epilogue -- saves the 13th K-tile the bias-fold cost)
__global__ __launch_bounds__(256, 2) void expert_gemm(
    const short* __restrict__ xs,      // [3][M][K]
    const short* __restrict__ Wb,      // [3][N][K] this layer
    const float* __restrict__ b_exp_l, // [3][N] this layer
    const float* __restrict__ g_sh,
    const float* __restrict__ g_t1,
    const float* __restrict__ g_t2,
    unsigned short* __restrict__ part) // [7][M][H] bf16
{
  __shared__ short lds[16384];  // 32 KiB: As[128][64] @0 | Bs[128][64] @8192 (shorts)

  const int bid = blockIdx.x;          // 4608 = 8 XCDs x 576
  const int xcd = bid & 7;
  const int idx = bid >> 3;            // 0..575
  const int t   = idx / 192;
  const int r2  = idx - t * 192;
  const int mt  = r2 / 6;
  const int m0  = mt * 128;
  const int n0  = (xcd * 6 + (r2 - mt * 6)) * 128;

  const short* A  = xs + (size_t)t * M_ * K_;
  const short* Bt = Wb + (size_t)t * N_ * K_;

  const int tid = threadIdx.x;
  const int w = tid >> 6, l = tid & 63;
  const int wr = w >> 1, wc = w & 1;   // 2 x 2 wave grid; per-wave 64x64

  // frag read offsets: row R = wr*64 + fm*16 + lr; phys slot = (ks*4+cg) ^ (lr>>1)
  const int lr = l & 15, cg = l >> 4;
  const int fx = lr >> 1;
  const int slot0 = ((cg ^ fx) << 3);            // ks=0  (shorts)
  const int slot1 = (((4 + cg) ^ fx) << 3);      // ks=1
  const int aoff = wr * 4096 + lr * 64;          // A base (shorts)
  const int boff = 8192 + wc * 4096 + lr * 64;   // B base

  f32x4 acc[4][4];
#pragma unroll
  for (int i = 0; i < 4; ++i)
#pragma unroll
    for (int j = 0; j < 4; ++j) acc[i][j] = (f32x4){0.f, 0.f, 0.f, 0.f};

  // staging: 4 rounds x (1 A + 1 B) gload_lds16; dest row = w*32+q*8+(l>>3), slot = l&7.
  // T2 swizzle inverse on global source: logical colgroup = (l&7) ^ ((q*4 + (l>>4)) & 7).
  for (int kt = 0; kt < NT; ++kt) {
    __syncthreads();                             // prev tile fully consumed
#pragma unroll
    for (int q = 0; q < 4; ++q) {
      const int row = w * 32 + q * 8 + (l >> 3);
      const int fq = (q * 4 + (l >> 4)) & 7;
      const int csw = ((l & 7) ^ fq) << 3;       // shorts
      gload_lds16(A  + (size_t)(m0 + row) * K_ + kt * 64 + csw, &lds[(w * 32 + q * 8) * 64]);
      gload_lds16(Bt + (size_t)(n0 + row) * K_ + kt * 64 + csw, &lds[8192 + (w * 32 + q * 8) * 64]);
    }
    __syncthreads();                             // staged tile visible (barrier drains vmcnt)

    bf16x8 a[4][2], b[4][2];
#pragma unroll
    for (int fm = 0; fm < 4; ++fm) {
      a[fm][0] = *(const bf16x8*)&lds[aoff + fm * 1024 + slot0];
      a[fm][1] = *(const bf16x8*)&lds[aoff + fm * 1024 + slot1];
    }
#pragma unroll
    for (int fn = 0; fn < 4; ++fn) {
      b[fn][0] = *(const bf16x8*)&lds[boff + fn * 1024 + slot0];
      b[fn][1] = *(const bf16x8*)&lds[boff + fn * 1024 + slot1];
    }
    __builtin_amdgcn_s_setprio(1);
#pragma unroll
    for (int ks = 0; ks < 2; ++ks)
#pragma unroll
      for (int fm = 0; fm < 4; ++fm)
#pragma unroll
        for (int fn = 0; fn < 4; ++fn)
          acc[fm][fn] = __builtin_amdgcn_mfma_f32_16x16x32_bf16(a[fm][ks], b[fn][ks], acc[fm][fn], 0, 0, 0);
    __builtin_amdgcn_s_setprio(0);
  }
  __syncthreads();   // staging LDS dead; safe to reuse for transpose

  // ---- epilogue: bias + gelu via wave-private LDS transpose + gated combine ----
  const size_t MH = (size_t)M_ * H_;
  const float *gpA, *gpB, *gpC = nullptr;
  unsigned short *ppA, *ppB, *ppC = nullptr;
  int ldA, ldB, ldC = 16, offA, offB, offC = 0, ntg;
  if (t == 0) {
    gpA = g_sh; ldA = 24; offA = 8; ppA = part;
    gpB = g_t1; ldB = 16; offB = 8; ppB = part + 1 * MH;
    gpC = g_t2; ldC = 16; offC = 8; ppC = part + 2 * MH; ntg = 3;
  } else if (t == 1) {
    gpA = g_sh; ldA = 24; offA = 0; ppA = part + 3 * MH;
    gpB = g_t1; ldB = 16; offB = 0; ppB = part + 4 * MH; ntg = 2;
  } else {
    gpA = g_sh; ldA = 24; offA = 16; ppA = part + 5 * MH;
    gpB = g_t2; ldB = 16; offB = 0;  ppB = part + 6 * MH; ntg = 2;
  }
  // per-lane bias for its 4 n-columns (n = n0 + wc*64 + fn*16 + lr); L3-resident table
  const float* be = b_exp_l + (size_t)t * N_ + n0 + wc * 64 + lr;
  float bias4[4];
#pragma unroll
  for (int fn = 0; fn < 4; ++fn) bias4[fn] = be[fn * 16];

  float* wtile = (float*)lds + w * 1040;         // 16 x 65 floats, wave-private
  const int xbase = (n0 + wc * 64) >> 3;
  const int xloc = l & 7;

#pragma unroll
  for (int fm = 0; fm < 4; ++fm) {
    // write 16 bias+gelu'd values into [16][65] tile (2-way banks max)
    asm volatile("s_waitcnt lgkmcnt(0)" ::: "memory");  // WAR vs prev fm's reads
#pragma unroll
    for (int fn = 0; fn < 4; ++fn)
#pragma unroll
      for (int r = 0; r < 4; ++r)
        wtile[(cg * 4 + r) * 65 + fn * 16 + lr] = gelu_fast(acc[fm][fn][r] + bias4[fn]);
    asm volatile("s_waitcnt lgkmcnt(0)" ::: "memory");  // RAW: writes visible to wave

    // read back: 2 (m,x) pairs per lane, 8 consecutive e-values each
    float v[2][8];
    int gm[2];
#pragma unroll
    for (int p = 0; p < 2; ++p) {
      const int mloc = p * 8 + (l >> 3);
      float4 v0 = *(const float4*)&wtile[mloc * 65 + xloc * 8];
      float4 v1 = *(const float4*)&wtile[mloc * 65 + xloc * 8 + 4];
      v[p][0] = v0.x; v[p][1] = v0.y; v[p][2] = v0.z; v[p][3] = v0.w;
      v[p][4] = v1.x; v[p][5] = v1.y; v[p][6] = v1.z; v[p][7] = v1.w;
      gm[p] = m0 + wr * 64 + fm * 16 + mloc;
    }

    // per stream: 2 float4 gate loads + 8 FMA + 1 bf16 store per (m,x)
#define DO_STREAM(gp, ldg, offg, pp)                                          \
    {                                                                         \
      _Pragma("unroll")                                                       \
      for (int p = 0; p < 2; ++p) {                                           \
        const float* gr = (gp) + (size_t)gm[p] * (ldg) + (offg);              \
        float4 ga = *(const float4*)gr;                                       \
        float4 gb = *(const float4*)(gr + 4);                                 \
        float o = ga.x * v[p][0] + ga.y * v[p][1] + ga.z * v[p][2]            \
                + ga.w * v[p][3] + gb.x * v[p][4] + gb.y * v[p][5]            \
                + gb.z * v[p][6] + gb.w * v[p][7];                            \
        (pp)[(size_t)gm[p] * H_ + xbase + xloc] = f2bf(o);                    \
      }                                                                       \
    }
    DO_STREAM(gpA, ldA, offA, ppA);
    DO_STREAM(gpB, ldB, offB, ppB);
    if (ntg == 3) DO_STREAM(gpC, ldC, offC, ppC);
#undef DO_STREAM
  }
}

// --------------------------------------------------------------- output heads
// 4 rows per block (512 thr): head-weight L2 re-reads divided by 4 vs 1-row blocks.
__global__ __launch_bounds__(512) void heads(
    const float* __restrict__ h,
    const unsigned short* __restrict__ part,
    const float* __restrict__ Wspan, const float* __restrict__ bspan,
    const float* __restrict__ Was,   const float* __restrict__ bas,
    const float* __restrict__ Wae,   const float* __restrict__ bae,
    float* __restrict__ out)
{
  const int base = blockIdx.x * 4;
  __shared__ float s1[4][768], s2[4][768];
  const size_t MH = (size_t)M_ * H_;
  for (int idx = threadIdx.x; idx < 4 * 768; idx += 512) {
    const int rr = idx / 768, i = idx - rr * 768;
    const int row = base + rr;
    s1[rr][i] = h[((size_t)M_ + row) * H_ + i]
              + bf2f(part[1 * MH + (size_t)row * H_ + i])
              + bf2f(part[4 * MH + (size_t)row * H_ + i]);
    s2[rr][i] = h[((size_t)2 * M_ + row) * H_ + i]
              + bf2f(part[2 * MH + (size_t)row * H_ + i])
              + bf2f(part[6 * MH + (size_t)row * H_ + i]);
  }
  __syncthreads();
  const int r = threadIdx.x >> 7;      // 0..3
  const int j = threadIdx.x & 127;
  const int row = base + r;
  const float* W; const float* src; float bias; float* op; int ldw;
  if (j < 5)       { W = Wspan + j;      src = s1[r]; bias = bspan[j];  op = out + (size_t)row * 5 + j;                ldw = 5;  }
  else if (j < 36) { W = Was + (j - 5);  src = s2[r]; bias = bas[j-5];  op = out + 20480 + (size_t)row * 31 + (j-5);   ldw = 31; }
  else if (j < 67) { W = Wae + (j - 36); src = s2[r]; bias = bae[j-36]; op = out + 147456 + (size_t)row * 31 + (j-36); ldw = 31; }
  else return;
  float acc = bias;
  for (int i = 0; i < 768; ++i) acc += src[i] * W[(size_t)i * ldw];
  *op = acc;
}

// ---------------------------------------------------------------------- launch
extern "C" void kernel_launch(void* const* d_in, const int* in_sizes, int n_in,
                              void* d_out, int out_size, void* d_ws, size_t ws_size,
                              hipStream_t stream) {
  (void)in_sizes; (void)n_in; (void)out_size; (void)ws_size;
  const float* share  = (const float*)d_in[0];
  const float* span   = (const float*)d_in[1];
  const float* attr   = (const float*)d_in[2];
  const float* ln_g   = (const float*)d_in[3];
  const float* ln_b   = (const float*)d_in[4];
  const float* W_exp  = (const float*)d_in[5];
  const float* b_exp  = (const float*)d_in[6];
  const float* Wg_sh  = (const float*)d_in[7];
  const float* bg_sh  = (const float*)d_in[8];
  const float* Wg_t1  = (const float*)d_in[9];
  const float* bg_t1  = (const float*)d_in[10];
  const float* Wg_t2  = (const float*)d_in[11];
  const float* bg_t2  = (const float*)d_in[12];
  const float* W_span = (const float*)d_in[13];
  const float* b_span = (const float*)d_in[14];
  const float* W_as   = (const float*)d_in[15];
  const float* b_as   = (const float*)d_in[16];
  const float* W_ae   = (const float*)d_in[17];
  const float* b_ae   = (const float*)d_in[18];

  // workspace layout (~126 MiB)
  char* ws = (char*)d_ws;
  short* Wb = (short*)ws;                                        // [3][N][K] bf16 (per layer)
  size_t o = (size_t)3 * N_ * K_ * 2;                            // 28,311,552
  short* xs = (short*)(ws + o); o += (size_t)3 * M_ * K_ * 2;    // 18,874,368
  float* h  = (float*)(ws + o); o += (size_t)3 * M_ * H_ * 4;    // 37,748,736
  float* gates = (float*)(ws + o); o += (size_t)M_ * (24 + 16 + 16) * 4;  // 917,504
  unsigned short* part = (unsigned short*)(ws + o);              // [7][M][H] bf16: 44,040,192

  for (int l = 0; l < L_; ++l) {
    conv_w<<<dim3(96, 12, 3), 256, 0, stream>>>(
        W_exp + (size_t)l * 3 * K_ * N_, Wb);
    ln_gates<<<768, 256, 0, stream>>>(
        share, span, attr, h, part, l, xs,
        ln_g + (size_t)l * 3 * H_, ln_b + (size_t)l * 3 * H_,
        Wg_sh + (size_t)l * H_ * 24, bg_sh + (size_t)l * 24,
        Wg_t1 + (size_t)l * H_ * 16, bg_t1 + (size_t)l * 16,
        Wg_t2 + (size_t)l * H_ * 16, bg_t2 + (size_t)l * 16,
        gates);
    expert_gemm<<<4608, 256, 0, stream>>>(
        xs, Wb, b_exp + (size_t)l * 3 * N_,
        gates, gates + (size_t)M_ * 24, gates + (size_t)M_ * 24 + (size_t)M_ * 16,
        part);
  }

  heads<<<1024, 512, 0, stream>>>(h, part, W_span, b_span, W_as, b_as, W_ae, b_ae,
                                  (float*)d_out);
}